// Round 11
// baseline (277.959 us; speedup 1.0000x reference)
//
#include <hip/hip_runtime.h>
#include <hip/hip_bf16.h>

typedef __attribute__((ext_vector_type(8))) short s8v;
typedef __attribute__((ext_vector_type(4))) float f4v;
typedef unsigned short us4 __attribute__((ext_vector_type(4)));
typedef unsigned short ushort_t;

#define NB 8192
#define ND 1024
#define NH 8
#define NU 1365
#define NUP 1408
#define GK 384
#define GN 512
static const size_t BD = (size_t)NB * ND;

// workspace layout (bytes)
#define WS_AG   ((size_t)0)          // bf16 [8192][3072]  A-operand for gates
#define WS_G    ((size_t)50331648)   // bf16 [8192][1408]  gated-MLP intermediate
#define WS_HBF  ((size_t)73400320)   // bf16 [8192][1024]  h_t
#define WS_WG   ((size_t)90177536)   // bf16 [4096][384]   gate weights, gate-interleaved cols
#define WS_ULR  ((size_t)93323264)   // bf16 [2816][1024]  interleaved upL/upR^T (16-col groups)
#define WS_DWNT ((size_t)99090432)   // bf16 [1024][1408]  down^T padded

__device__ __forceinline__ void gload16(const void* g, void* l) {
  __builtin_amdgcn_global_load_lds((const __attribute__((address_space(1))) void*)g,
                                   (__attribute__((address_space(3))) void*)l, 16, 0, 0);
}
__device__ __forceinline__ unsigned short tobf(float f) {
  unsigned int u = __float_as_uint(f);
  unsigned int r = (u + 0x7FFFu + ((u >> 16) & 1u)) >> 16;
  return (unsigned short)r;
}
__device__ __forceinline__ float frcp(float x) { return __builtin_amdgcn_rcpf(x); }
__device__ __forceinline__ float fsigm(float x) { return frcp(1.f + __expf(-x)); }
__device__ __forceinline__ float ftanh(float x) {
  float e = __expf(2.f * x);
  return 1.f - 2.f * frcp(e + 1.f);
}
__device__ __forceinline__ f4v mfma16(s8v a, s8v b, f4v c) {
  return __builtin_amdgcn_mfma_f32_16x16x32_bf16(a, b, c, 0, 0, 0);
}

// ---------------- weight prep: bf16 pack / transpose / pad / interleave ----------------
__global__ __launch_bounds__(256) void prep_kernel(
    const float* __restrict__ W, const float* __restrict__ R,
    const float* __restrict__ upl, const float* __restrict__ upr,
    const float* __restrict__ dwn,
    unsigned short* __restrict__ Wg, unsigned short* __restrict__ ULR,
    unsigned short* __restrict__ Dt) {
  long long idx = (long long)blockIdx.x * 256 + threadIdx.x;
  const long long N1 = (long long)4096 * GK;
  const long long N3 = (long long)2 * NUP * ND;
  const long long N2 = (long long)NUP * ND;
  if (idx < N1) {
    int c = (int)(idx / GK), k = (int)(idx % GK);
    int j = c & 15, g = (c >> 4) & 3, cgrp = (c >> 6) & 7, h = c >> 9;
    int o = cgrp * 16 + j;
    float v = 0.f;
    if (k < 128) {
      if (g == 0 || g == 3) v = W[(((size_t)g * NH + h) * 128 + k) * 128 + o];
    } else if (k < 256) {
      if (g == 1 || g == 2) v = W[(((size_t)g * NH + h) * 128 + (k - 128)) * 128 + o];
    } else {
      v = R[(((size_t)g * NH + h) * 128 + (k - 256)) * 128 + o];
    }
    Wg[idx] = tobf(v);
    return;
  }
  idx -= N1;
  if (idx < N3) {
    int r = (int)(idx / ND), k = (int)(idx % ND);
    int o = (r >> 4) & 1;
    int gcol = (r >> 5) * 16 + (r & 15);
    float v = 0.f;
    if (gcol < NU) v = o ? upr[(size_t)k * NU + gcol] : upl[(size_t)k * NU + gcol];
    ULR[idx] = tobf(v);
    return;
  }
  idx -= N3;
  if (idx < N2) { int n = (int)(idx / NUP), k = (int)(idx % NUP);
    Dt[idx] = (k < NU) ? tobf(dwn[(size_t)k * ND + n]) : 0; return; }
}

// ---------------- LayerNorm + causal conv1d + SiLU; emit gate A-operand ----------------
__global__ __launch_bounds__(256) void norm_conv(
    const float* __restrict__ x, const float* __restrict__ hp,
    const float* __restrict__ lg, const float* __restrict__ lb,
    const float* __restrict__ cw, const float* __restrict__ cb,
    unsigned short* __restrict__ Ag) {
  const int b = blockIdx.x, tid = threadIdx.x;
  const int lane = tid & 63, wv = tid >> 6;
  __shared__ float xs[1024];
  __shared__ float red[8];
  const int d0 = tid * 4;
  float4 xv = *(const float4*)(x + (size_t)b * ND + d0);
  float s = xv.x + xv.y + xv.z + xv.w;
  float ss = xv.x * xv.x + xv.y * xv.y + xv.z * xv.z + xv.w * xv.w;
#pragma unroll
  for (int o = 32; o; o >>= 1) { s += __shfl_down(s, o); ss += __shfl_down(ss, o); }
  if (lane == 0) { red[wv] = s; red[4 + wv] = ss; }
  __syncthreads();
  float S = red[0] + red[1] + red[2] + red[3];
  float SS = red[4] + red[5] + red[6] + red[7];
  float mu = S * (1.f / ND);
  float var = SS * (1.f / ND) - mu * mu;
  float rstd = rsqrtf(var + 1e-5f);
  float xn[4];
#pragma unroll
  for (int t = 0; t < 4; ++t) {
    float xx = (&xv.x)[t];
    xn[t] = (xx - mu) * rstd * lg[d0 + t] + lb[d0 + t];
    xs[d0 + t] = xn[t];
  }
  __syncthreads();
  float w0 = cw[0], w1 = cw[1], w2 = cw[2], w3 = cw[3], cbv = cb[0];
  float cv[4];
#pragma unroll
  for (int t = 0; t < 4; ++t) {
    int d = d0 + t;
    float a = cbv + w3 * xs[d];
    if (d >= 1) a += w2 * xs[d - 1];
    if (d >= 2) a += w1 * xs[d - 2];
    if (d >= 3) a += w0 * xs[d - 3];
    cv[t] = a * fsigm(a);
  }
  float4 hv = *(const float4*)(hp + (size_t)b * ND + d0);
  const int h = d0 >> 7, j = d0 & 127;
  us4 px, pc, ph;
#pragma unroll
  for (int t = 0; t < 4; ++t) { px[t] = tobf((&xv.x)[t]); pc[t] = tobf(cv[t]); ph[t] = tobf((&hv.x)[t]); }
  size_t base = (size_t)b * 3072 + (size_t)h * 384 + j;
  *(us4*)(Ag + base) = px;
  *(us4*)(Ag + base + 128) = pc;
  *(us4*)(Ag + base + 256) = ph;
}

// ---------------- fused gate GEMM + sLSTM state update (R9/R10 best) ----------------
__global__ __launch_bounds__(256) void gate_fused(
    const unsigned short* __restrict__ Ag, const unsigned short* __restrict__ Wg,
    const float* __restrict__ bW, const float* __restrict__ bR,
    const float* __restrict__ cp, const float* __restrict__ np_,
    const float* __restrict__ mp,
    float* __restrict__ dout, unsigned short* __restrict__ Hb) {
  __shared__ short As[128 * 32];
  __shared__ short Bs[128 * 32];
  const int tid = threadIdx.x, lane = tid & 63, wv = tid >> 6;
  const int wm = wv >> 1, wn = wv & 1;
  const int row0 = blockIdx.x * 128;
  const int p = blockIdx.y;
  const int h = blockIdx.z;
  const int srow = wv * 32 + (lane >> 2), scol = (lane & 3) * 8;
  const unsigned short* At = Ag + (size_t)h * 384;
  const unsigned short* Bt = Wg + ((size_t)h * 512 + (size_t)p * 128) * GK;
  const int cgrp = p * 2 + wn;
  const int gcol = h * 128 + cgrp * 16 + (lane & 15);
  float pc_[16], pn_[16], pm_[16];
#pragma unroll
  for (int m = 0; m < 4; ++m)
#pragma unroll
    for (int r = 0; r < 4; ++r) {
      const size_t idx = (size_t)(row0 + wm * 64 + m * 16 + (lane >> 4) * 4 + r) * ND + gcol;
      pc_[m * 4 + r] = cp[idx];
      pn_[m * 4 + r] = np_[idx];
      pm_[m * 4 + r] = mp[idx];
    }
  f4v acc[4][4] = {};
#pragma unroll
  for (int kt = 0; kt < 12; ++kt) {
    const int k0 = kt * 32;
    gload16(At + (size_t)(row0 + srow) * 3072 + k0 + scol, (char*)As + wv * 2048);
    gload16(At + (size_t)(row0 + srow + 16) * 3072 + k0 + scol, (char*)As + wv * 2048 + 1024);
    gload16(Bt + (size_t)srow * GK + k0 + scol, (char*)Bs + wv * 2048);
    gload16(Bt + (size_t)(srow + 16) * GK + k0 + scol, (char*)Bs + wv * 2048 + 1024);
    __syncthreads();
    s8v a[4];
#pragma unroll
    for (int m = 0; m < 4; ++m)
      a[m] = *(const s8v*)&As[(wm * 64 + m * 16 + (lane & 15)) * 32 + (lane >> 4) * 8];
#pragma unroll
    for (int g = 0; g < 4; ++g) {
      const bool active = (kt >= 8) || (kt < 4 ? (g == 0 || g == 3) : (g == 1 || g == 2));
      if (active) {
        s8v b = *(const s8v*)&Bs[(wn * 64 + g * 16 + (lane & 15)) * 32 + (lane >> 4) * 8];
#pragma unroll
        for (int m = 0; m < 4; ++m) acc[m][g] = mfma16(a[m], b, acc[m][g]);
      }
    }
    __syncthreads();
  }
  const float Bz = bW[gcol] + bR[gcol];
  const float Bi = bW[ND + gcol] + bR[ND + gcol];
  const float Bf = bW[2 * ND + gcol] + bR[2 * ND + gcol];
  const float Bo = bW[3 * ND + gcol] + bR[3 * ND + gcol];
#pragma unroll
  for (int m = 0; m < 4; ++m) {
    const int rbase = row0 + wm * 64 + m * 16 + (lane >> 4) * 4;
#pragma unroll
    for (int r = 0; r < 4; ++r) {
      const int e = m * 4 + r;
      const size_t idx = (size_t)(rbase + r) * ND + gcol;
      float zt = ftanh(acc[m][0][r] + Bz);
      float it = acc[m][1][r] + Bi;
      float ft = acc[m][2][r] + Bf;
      float ot = fsigm(acc[m][3][r] + Bo);
      float mv = pm_[e];
      float mt = fmaxf(ft + mv, it);
      float ii = __expf(it - mt);
      float ff = __expf(ft + mv - mt);
      float ct = ff * pc_[e] + ii * zt;
      float nt = ff * pn_[e] + ii;
      float ht = ot * ct * frcp(nt);
      dout[BD + idx] = ht;
      dout[2 * BD + idx] = ct;
      dout[3 * BD + idx] = nt;
      dout[4 * BD + idx] = mt;
      Hb[idx] = tobf(ht);
    }
  }
}

// ================= 8-phase 256x128xBK64 GEMM core =================
// 8 waves (512 thr). Quadrants (mh,nh): (0,0),(1,0),(1,1),(0,1).
// Staging: p1 -> A0,B1(u+1) into free buf; p3 -> B0(u+2); p4 -> A1(u+2) into live buf
// (each half's last LDS-read is >=1 barrier before its overwrite). One counted
// vmcnt(3) per K-tile. st_16x32 swizzle: linear LDS dest + pre-swizzled global
// source + swizzled ds_read (rule #21).

__device__ __forceinline__ void stage_a_half(
    const unsigned short* __restrict__ Ab, int ldA, int row0, int t, int mh,
    short* lds, int wid, int lane) {
#pragma unroll
  for (int q = 0; q < 2; ++q) {
    const int ldsrow = mh * 128 + (wid * 2 + q) * 8;
    const int g = (lane & 7) ^ (((lane >> 5) & 1) << 1);
    gload16(Ab + (size_t)(row0 + ldsrow + (lane >> 3)) * ldA + t * 64 + g * 8,
            lds + ldsrow * 64);
  }
}
__device__ __forceinline__ void stage_b_half(
    const unsigned short* __restrict__ Bb, int ldB, int n0, int t, int nh,
    short* lds, int wid, int lane) {
  const int ldsrow = nh * 64 + wid * 8;
  const int g = (lane & 7) ^ (((lane >> 5) & 1) << 1);
  gload16(Bb + (size_t)(n0 + ldsrow + (lane >> 3)) * ldB + t * 64 + g * 8,
          lds + ldsrow * 64);
}

#define DS_A(MH)                                                                 \
  _Pragma("unroll") for (int mf = 0; mf < 2; ++mf)                               \
  _Pragma("unroll") for (int kk = 0; kk < 2; ++kk) {                             \
    const int rr_ = (MH) * 128 + (wid >> 1) * 32 + mf * 16 + (lane & 15);        \
    const int ix_ = (rr_ * 64 + kk * 32 + ((lane >> 4) & 3) * 8) ^               \
                    (((rr_ >> 2) & 1) << 4);                                     \
    av[mf][kk] = *(const s8v*)&As[cur][ix_];                                     \
  }
#define DS_B(NH)                                                                 \
  _Pragma("unroll") for (int nf = 0; nf < 2; ++nf)                               \
  _Pragma("unroll") for (int kk = 0; kk < 2; ++kk) {                             \
    const int rr_ = (NH) * 64 + (wid & 1) * 32 + nf * 16 + (lane & 15);          \
    const int ix_ = (rr_ * 64 + kk * 32 + ((lane >> 4) & 3) * 8) ^               \
                    (((rr_ >> 2) & 1) << 4);                                     \
    bv[nf][kk] = *(const s8v*)&Bs[cur][ix_];                                     \
  }
#define PHASE_MM(MH, NH)                                                         \
  __builtin_amdgcn_s_barrier();                                                  \
  asm volatile("s_waitcnt lgkmcnt(0)" ::: "memory");                             \
  __builtin_amdgcn_sched_barrier(0);                                             \
  __builtin_amdgcn_s_setprio(1);                                                 \
  _Pragma("unroll") for (int kk = 0; kk < 2; ++kk)                               \
  _Pragma("unroll") for (int mf = 0; mf < 2; ++mf)                               \
  _Pragma("unroll") for (int nf = 0; nf < 2; ++nf)                               \
    acc[(MH) * 2 + mf][(NH) * 2 + nf] =                                          \
        mfma16(av[mf][kk], bv[nf][kk], acc[(MH) * 2 + mf][(NH) * 2 + nf]);       \
  __builtin_amdgcn_s_setprio(0);                                                 \
  __builtin_amdgcn_sched_barrier(0);

#define GEMM8_BODY(Aptr, LDA, Bptr, LDB, NT)                                     \
  stage_a_half(Aptr, LDA, row0, 0, 0, &As[0][0], wid, lane);                     \
  stage_b_half(Bptr, LDB, n0, 0, 0, &Bs[0][0], wid, lane);                       \
  stage_a_half(Aptr, LDA, row0, 0, 1, &As[0][0], wid, lane);                     \
  stage_b_half(Bptr, LDB, n0, 0, 1, &Bs[0][0], wid, lane);                       \
  stage_b_half(Bptr, LDB, n0, 1, 0, &Bs[1][0], wid, lane);                       \
  stage_a_half(Aptr, LDA, row0, 1, 1, &As[1][0], wid, lane);                     \
  asm volatile("s_waitcnt vmcnt(3)" ::: "memory");                               \
  __builtin_amdgcn_s_barrier();                                                  \
  for (int u = 0; u < (NT); ++u) {                                               \
    const int cur = u & 1, nxt = cur ^ 1;                                        \
    s8v av[2][2], bv[2][2];                                                      \
    /* p1: q(0,0); stage A0,B1 of tile u+1 into free buffer */                   \
    DS_A(0); DS_B(0);                                                            \
    if (u + 1 < (NT)) {                                                          \
      stage_a_half(Aptr, LDA, row0, u + 1, 0, &As[nxt][0], wid, lane);           \
      stage_b_half(Bptr, LDB, n0, u + 1, 1, &Bs[nxt][0], wid, lane);             \
    }                                                                            \
    PHASE_MM(0, 0);                                                              \
    __builtin_amdgcn_s_barrier();                                                \
    /* p2: q(1,0) */                                                             \
    DS_A(1);                                                                     \
    PHASE_MM(1, 0);                                                              \
    __builtin_amdgcn_s_barrier();                                                \
    /* p3: q(1,1); stage B0(u+2) into live buffer (B0 reads done at p2) */       \
    DS_B(1);                                                                     \
    if (u + 2 < (NT)) stage_b_half(Bptr, LDB, n0, u + 2, 0, &Bs[cur][0], wid, lane); \
    PHASE_MM(1, 1);                                                              \
    __builtin_amdgcn_s_barrier();                                                \
    /* p4: q(0,1); stage A1(u+2) (A1 reads done at p2) */                        \
    DS_A(0);                                                                     \
    if (u + 2 < (NT)) stage_a_half(Aptr, LDA, row0, u + 2, 1, &As[cur][0], wid, lane); \
    PHASE_MM(0, 1);                                                              \
    if (u + 2 < (NT)) { asm volatile("s_waitcnt vmcnt(3)" ::: "memory"); }       \
    else              { asm volatile("s_waitcnt vmcnt(0)" ::: "memory"); }       \
    __builtin_amdgcn_s_barrier();                                                \
  }

// ---------------- up GEMM, 8-phase, fused GLU epilogue -> bf16 G ----------------
__global__ __launch_bounds__(512) void up8_gemm(
    const unsigned short* __restrict__ A, const unsigned short* __restrict__ ULR,
    const float* __restrict__ lbias, const float* __restrict__ rbias,
    unsigned short* __restrict__ G) {
  __shared__ short As[2][16384];   // [256 rows][64 k] x2  (64KB)
  __shared__ short Bs[2][8192];    // [128 rows][64 k] x2  (32KB)
  const int tid = threadIdx.x, lane = tid & 63, wid = tid >> 6;
  const int bid = blockIdx.x;
  const int swz = (bid & 7) * 88 + (bid >> 3);    // 704 = 8*88, bijective
  const int row0 = (swz / 22) * 256, n0 = (swz % 22) * 128;
  f4v acc[4][4] = {};
  GEMM8_BODY(A, 1024, ULR, 1024, 16);
#pragma unroll
  for (int mh = 0; mh < 2; ++mh)
#pragma unroll
  for (int mf = 0; mf < 2; ++mf) {
    const int rbase = row0 + mh * 128 + (wid >> 1) * 32 + mf * 16 + (lane >> 4) * 4;
#pragma unroll
    for (int nh = 0; nh < 2; ++nh) {
      const int gcol = ((n0 + nh * 64 + (wid & 1) * 32) >> 1) + (lane & 15);
      const bool ok = gcol < NU;
      const float bl_ = ok ? lbias[gcol] : 0.f;
      const float br_ = ok ? rbias[gcol] : 0.f;
#pragma unroll
      for (int r = 0; r < 4; ++r) {
        float L = acc[mh * 2 + mf][nh * 2 + 0][r] + bl_;
        float Rv = acc[mh * 2 + mf][nh * 2 + 1][r] + br_;
        float ge = 0.5f * Rv * (1.f + erff(Rv * 0.70710678118654752f));
        G[(size_t)(rbase + r) * NUP + gcol] = ok ? tobf(L * ge) : (unsigned short)0;
      }
    }
  }
}

// ---------------- down GEMM, 8-phase: G @ down^T + bias -> output ----------------
__global__ __launch_bounds__(512) void down8_gemm(
    const unsigned short* __restrict__ A, const unsigned short* __restrict__ Bt,
    const float* __restrict__ dbias, float* __restrict__ out) {
  __shared__ short As[2][16384];
  __shared__ short Bs[2][8192];
  const int tid = threadIdx.x, lane = tid & 63, wid = tid >> 6;
  const int bid = blockIdx.x;
  const int swz = (bid & 7) * 32 + (bid >> 3);    // 256 = 8*32, bijective
  const int row0 = (swz >> 3) * 256, n0 = (swz & 7) * 128;
  f4v acc[4][4] = {};
  GEMM8_BODY(A, NUP, Bt, NUP, 22);
#pragma unroll
  for (int mh = 0; mh < 2; ++mh)
#pragma unroll
  for (int mf = 0; mf < 2; ++mf) {
    const int rbase = row0 + mh * 128 + (wid >> 1) * 32 + mf * 16 + (lane >> 4) * 4;
#pragma unroll
    for (int nh = 0; nh < 2; ++nh)
#pragma unroll
    for (int nf = 0; nf < 2; ++nf) {
      const int col = n0 + nh * 64 + (wid & 1) * 32 + nf * 16 + (lane & 15);
      const float bias = dbias[col];
#pragma unroll
      for (int r = 0; r < 4; ++r)
        out[(size_t)(rbase + r) * ND + col] = acc[mh * 2 + mf][nh * 2 + nf][r] + bias;
    }
  }
}

extern "C" void kernel_launch(void* const* d_in, const int* in_sizes, int n_in,
                              void* d_out, int out_size, void* d_ws, size_t ws_size,
                              hipStream_t stream) {
  const float* x    = (const float*)d_in[0];
  const float* hp   = (const float*)d_in[1];
  const float* cp   = (const float*)d_in[2];
  const float* np_  = (const float*)d_in[3];
  const float* mp   = (const float*)d_in[4];
  const float* lg   = (const float*)d_in[5];
  const float* lb   = (const float*)d_in[6];
  const float* cw   = (const float*)d_in[7];
  const float* cb   = (const float*)d_in[8];
  const float* W    = (const float*)d_in[9];
  const float* bW   = (const float*)d_in[10];
  const float* R    = (const float*)d_in[11];
  const float* bR   = (const float*)d_in[12];
  const float* upl  = (const float*)d_in[13];
  const float* uplb = (const float*)d_in[14];
  const float* upr  = (const float*)d_in[15];
  const float* uprb = (const float*)d_in[16];
  const float* dwn  = (const float*)d_in[17];
  const float* dwnb = (const float*)d_in[18];
  float* out = (float*)d_out;
  char* ws = (char*)d_ws;
  unsigned short* Ag  = (unsigned short*)(ws + WS_AG);
  unsigned short* G   = (unsigned short*)(ws + WS_G);
  unsigned short* Hb  = (unsigned short*)(ws + WS_HBF);
  unsigned short* Wg  = (unsigned short*)(ws + WS_WG);
  unsigned short* ULR = (unsigned short*)(ws + WS_ULR);
  unsigned short* Dt  = (unsigned short*)(ws + WS_DWNT);

  prep_kernel<<<23040, 256, 0, stream>>>(W, R, upl, upr, dwn, Wg, ULR, Dt);
  norm_conv<<<NB, 256, 0, stream>>>(x, hp, lg, lb, cw, cb, Ag);
  gate_fused<<<dim3(64, 4, 8), 256, 0, stream>>>(Ag, Wg, bW, bR, cp, np_, mp, out, Hb);
  up8_gemm<<<704, 512, 0, stream>>>(Hb, ULR, uplb, uprb, G);
  down8_gemm<<<256, 512, 0, stream>>>(G, Dt, dwnb, out);
}

// Round 12
// 264.815 us; speedup vs baseline: 1.0496x; 1.0496x over previous
//
#include <hip/hip_runtime.h>
#include <hip/hip_bf16.h>

typedef __attribute__((ext_vector_type(8))) short s8v;
typedef __attribute__((ext_vector_type(4))) float f4v;
typedef unsigned short us4 __attribute__((ext_vector_type(4)));

#define NB 8192
#define ND 1024
#define NH 8
#define NU 1365
#define NUP 1408
#define GK 384
#define GN 512
static const size_t BD = (size_t)NB * ND;

// workspace layout (bytes)
#define WS_AG   ((size_t)0)          // bf16 [8192][3072]  A-operand for gates
#define WS_G    ((size_t)50331648)   // bf16 [8192][1408]  gated-MLP intermediate
#define WS_HBF  ((size_t)73400320)   // bf16 [8192][1024]  h_t
#define WS_WG   ((size_t)90177536)   // bf16 [4096][384]   gate weights, gate-interleaved cols
#define WS_ULR  ((size_t)93323264)   // bf16 [2816][1024]  interleaved upL/upR^T (16-col groups)
#define WS_DWNT ((size_t)99090432)   // bf16 [1024][1408]  down^T padded

__device__ __forceinline__ void gload16(const void* g, void* l) {
  __builtin_amdgcn_global_load_lds((const __attribute__((address_space(1))) void*)g,
                                   (__attribute__((address_space(3))) void*)l, 16, 0, 0);
}
__device__ __forceinline__ unsigned short tobf(float f) {
  unsigned int u = __float_as_uint(f);
  unsigned int r = (u + 0x7FFFu + ((u >> 16) & 1u)) >> 16;
  return (unsigned short)r;
}
__device__ __forceinline__ float frcp(float x) { return __builtin_amdgcn_rcpf(x); }
__device__ __forceinline__ float fsigm(float x) { return frcp(1.f + __expf(-x)); }
__device__ __forceinline__ float ftanh(float x) {
  float e = __expf(2.f * x);
  return 1.f - 2.f * frcp(e + 1.f);
}
__device__ __forceinline__ f4v mfma16(s8v a, s8v b, f4v c) {
  return __builtin_amdgcn_mfma_f32_16x16x32_bf16(a, b, c, 0, 0, 0);
}

// ---------------- weight prep: bf16 pack / transpose / pad / interleave ----------------
__global__ __launch_bounds__(256) void prep_kernel(
    const float* __restrict__ W, const float* __restrict__ R,
    const float* __restrict__ upl, const float* __restrict__ upr,
    const float* __restrict__ dwn,
    unsigned short* __restrict__ Wg, unsigned short* __restrict__ ULR,
    unsigned short* __restrict__ Dt) {
  long long idx = (long long)blockIdx.x * 256 + threadIdx.x;
  const long long N1 = (long long)4096 * GK;
  const long long N3 = (long long)2 * NUP * ND;
  const long long N2 = (long long)NUP * ND;
  if (idx < N1) {
    int c = (int)(idx / GK), k = (int)(idx % GK);
    int j = c & 15, g = (c >> 4) & 3, cgrp = (c >> 6) & 7, h = c >> 9;
    int o = cgrp * 16 + j;
    float v = 0.f;
    if (k < 128) {
      if (g == 0 || g == 3) v = W[(((size_t)g * NH + h) * 128 + k) * 128 + o];
    } else if (k < 256) {
      if (g == 1 || g == 2) v = W[(((size_t)g * NH + h) * 128 + (k - 128)) * 128 + o];
    } else {
      v = R[(((size_t)g * NH + h) * 128 + (k - 256)) * 128 + o];
    }
    Wg[idx] = tobf(v);
    return;
  }
  idx -= N1;
  if (idx < N3) {
    int r = (int)(idx / ND), k = (int)(idx % ND);
    int o = (r >> 4) & 1;
    int gcol = (r >> 5) * 16 + (r & 15);
    float v = 0.f;
    if (gcol < NU) v = o ? upr[(size_t)k * NU + gcol] : upl[(size_t)k * NU + gcol];
    ULR[idx] = tobf(v);
    return;
  }
  idx -= N3;
  if (idx < N2) { int n = (int)(idx / NUP), k = (int)(idx % NUP);
    Dt[idx] = (k < NU) ? tobf(dwn[(size_t)k * ND + n]) : 0; return; }
}

// ---------------- LayerNorm + causal conv1d + SiLU; emit gate A-operand ----------------
__global__ __launch_bounds__(256) void norm_conv(
    const float* __restrict__ x, const float* __restrict__ hp,
    const float* __restrict__ lg, const float* __restrict__ lb,
    const float* __restrict__ cw, const float* __restrict__ cb,
    unsigned short* __restrict__ Ag) {
  const int b = blockIdx.x, tid = threadIdx.x;
  const int lane = tid & 63, wv = tid >> 6;
  __shared__ float xs[1024];
  __shared__ float red[8];
  const int d0 = tid * 4;
  float4 xv = *(const float4*)(x + (size_t)b * ND + d0);
  float s = xv.x + xv.y + xv.z + xv.w;
  float ss = xv.x * xv.x + xv.y * xv.y + xv.z * xv.z + xv.w * xv.w;
#pragma unroll
  for (int o = 32; o; o >>= 1) { s += __shfl_down(s, o); ss += __shfl_down(ss, o); }
  if (lane == 0) { red[wv] = s; red[4 + wv] = ss; }
  __syncthreads();
  float S = red[0] + red[1] + red[2] + red[3];
  float SS = red[4] + red[5] + red[6] + red[7];
  float mu = S * (1.f / ND);
  float var = SS * (1.f / ND) - mu * mu;
  float rstd = rsqrtf(var + 1e-5f);
  float xn[4];
#pragma unroll
  for (int t = 0; t < 4; ++t) {
    float xx = (&xv.x)[t];
    xn[t] = (xx - mu) * rstd * lg[d0 + t] + lb[d0 + t];
    xs[d0 + t] = xn[t];
  }
  __syncthreads();
  float w0 = cw[0], w1 = cw[1], w2 = cw[2], w3 = cw[3], cbv = cb[0];
  float cv[4];
#pragma unroll
  for (int t = 0; t < 4; ++t) {
    int d = d0 + t;
    float a = cbv + w3 * xs[d];
    if (d >= 1) a += w2 * xs[d - 1];
    if (d >= 2) a += w1 * xs[d - 2];
    if (d >= 3) a += w0 * xs[d - 3];
    cv[t] = a * fsigm(a);
  }
  float4 hv = *(const float4*)(hp + (size_t)b * ND + d0);
  const int h = d0 >> 7, j = d0 & 127;
  us4 px, pc, ph;
#pragma unroll
  for (int t = 0; t < 4; ++t) { px[t] = tobf((&xv.x)[t]); pc[t] = tobf(cv[t]); ph[t] = tobf((&hv.x)[t]); }
  size_t base = (size_t)b * 3072 + (size_t)h * 384 + j;
  *(us4*)(Ag + base) = px;
  *(us4*)(Ag + base + 128) = pc;
  *(us4*)(Ag + base + 256) = ph;
}

// ---------------- fused gate GEMM + sLSTM state update ----------------
// 3-buffer, 2-tiles-ahead pipeline: vmcnt(4) counted wait -> s_barrier ->
// stage tile u+2 -> ds_read+MFMA. One barrier/iter; vmcnt never 0 mid-loop.
__global__ __launch_bounds__(256) void gate_fused(
    const unsigned short* __restrict__ Ag, const unsigned short* __restrict__ Wg,
    const float* __restrict__ bW, const float* __restrict__ bR,
    const float* __restrict__ cp, const float* __restrict__ np_,
    const float* __restrict__ mp,
    float* __restrict__ dout, unsigned short* __restrict__ Hb) {
  __shared__ short As[3][4096];
  __shared__ short Bs[3][4096];
  const int tid = threadIdx.x, lane = tid & 63, wv = tid >> 6;
  const int wm = wv >> 1, wn = wv & 1;
  const int row0 = blockIdx.x * 128;
  const int p = blockIdx.y;
  const int h = blockIdx.z;
  const int srow = wv * 32 + (lane >> 2), scol = (lane & 3) * 8;
  const unsigned short* At = Ag + (size_t)h * 384;
  const unsigned short* Bt = Wg + ((size_t)h * 512 + (size_t)p * 128) * GK;
  const int cgrp = p * 2 + wn;
  const int gcol = h * 128 + cgrp * 16 + (lane & 15);
  float pc_[16], pn_[16], pm_[16];
#pragma unroll
  for (int m = 0; m < 4; ++m)
#pragma unroll
    for (int r = 0; r < 4; ++r) {
      const size_t idx = (size_t)(row0 + wm * 64 + m * 16 + (lane >> 4) * 4 + r) * ND + gcol;
      pc_[m * 4 + r] = cp[idx];
      pn_[m * 4 + r] = np_[idx];
      pm_[m * 4 + r] = mp[idx];
    }
#define STGG(bb, kt_)                                                                   \
  do {                                                                                  \
    const int k0_ = (kt_) * 32;                                                         \
    gload16(At + (size_t)(row0 + srow) * 3072 + k0_ + scol, (char*)As[bb] + wv * 2048); \
    gload16(At + (size_t)(row0 + srow + 16) * 3072 + k0_ + scol,                        \
            (char*)As[bb] + wv * 2048 + 1024);                                          \
    gload16(Bt + (size_t)srow * GK + k0_ + scol, (char*)Bs[bb] + wv * 2048);            \
    gload16(Bt + (size_t)(srow + 16) * GK + k0_ + scol,                                 \
            (char*)Bs[bb] + wv * 2048 + 1024);                                          \
  } while (0)
  f4v acc[4][4] = {};
  STGG(0, 0);
  STGG(1, 1);
  for (int kt = 0; kt < 12; ++kt) {
    const int cur = kt % 3;
    if (kt < 11) asm volatile("s_waitcnt vmcnt(4)" ::: "memory");
    else         asm volatile("s_waitcnt vmcnt(0)" ::: "memory");
    asm volatile("s_barrier" ::: "memory");
    if (kt + 2 < 12) STGG((kt + 2) % 3, kt + 2);
    s8v a[4];
#pragma unroll
    for (int m = 0; m < 4; ++m)
      a[m] = *(const s8v*)&As[cur][(wm * 64 + m * 16 + (lane & 15)) * 32 + (lane >> 4) * 8];
#pragma unroll
    for (int g = 0; g < 4; ++g) {
      const bool active = (kt >= 8) || (kt < 4 ? (g == 0 || g == 3) : (g == 1 || g == 2));
      if (active) {
        s8v b = *(const s8v*)&Bs[cur][(wn * 64 + g * 16 + (lane & 15)) * 32 + (lane >> 4) * 8];
#pragma unroll
        for (int m = 0; m < 4; ++m) acc[m][g] = mfma16(a[m], b, acc[m][g]);
      }
    }
  }
#undef STGG
  const float Bz = bW[gcol] + bR[gcol];
  const float Bi = bW[ND + gcol] + bR[ND + gcol];
  const float Bf = bW[2 * ND + gcol] + bR[2 * ND + gcol];
  const float Bo = bW[3 * ND + gcol] + bR[3 * ND + gcol];
#pragma unroll
  for (int m = 0; m < 4; ++m) {
    const int rbase = row0 + wm * 64 + m * 16 + (lane >> 4) * 4;
#pragma unroll
    for (int r = 0; r < 4; ++r) {
      const int e = m * 4 + r;
      const size_t idx = (size_t)(rbase + r) * ND + gcol;
      float zt = ftanh(acc[m][0][r] + Bz);
      float it = acc[m][1][r] + Bi;
      float ft = acc[m][2][r] + Bf;
      float ot = fsigm(acc[m][3][r] + Bo);
      float mv = pm_[e];
      float mt = fmaxf(ft + mv, it);
      float ii = __expf(it - mt);
      float ff = __expf(ft + mv - mt);
      float ct = ff * pc_[e] + ii * zt;
      float nt = ff * pn_[e] + ii;
      float ht = ot * ct * frcp(nt);
      dout[BD + idx] = ht;
      dout[2 * BD + idx] = ct;
      dout[3 * BD + idx] = nt;
      dout[4 * BD + idx] = mt;
      Hb[idx] = tobf(ht);
    }
  }
}

// ---------------- up GEMM, 3-buffer pipelined; fused GLU epilogue -> bf16 G ----------------
__global__ __launch_bounds__(256) void up_gemm(
    const unsigned short* __restrict__ A, const unsigned short* __restrict__ ULR,
    const float* __restrict__ lbias, const float* __restrict__ rbias,
    unsigned short* __restrict__ G) {
  __shared__ short As[3][4096];
  __shared__ short Bs[3][4096];
  const int tid = threadIdx.x, lane = tid & 63, wv = tid >> 6;
  const int wm = wv >> 1, wn = wv & 1;
  const int bid = blockIdx.x;
  const int swz = (bid & 7) * 176 + (bid >> 3);   // 1408 = 8*176, bijective
  const int row0 = (swz / 22) * 128, n0 = (swz % 22) * 128;
  const int srow = wv * 32 + (lane >> 2), scol = (lane & 3) * 8;
#define STGU(bb, kt_)                                                                     \
  do {                                                                                    \
    const int k0_ = (kt_) * 32;                                                           \
    gload16(A + (size_t)(row0 + srow) * 1024 + k0_ + scol, (char*)As[bb] + wv * 2048);    \
    gload16(A + (size_t)(row0 + srow + 16) * 1024 + k0_ + scol,                           \
            (char*)As[bb] + wv * 2048 + 1024);                                            \
    gload16(ULR + (size_t)(n0 + srow) * 1024 + k0_ + scol, (char*)Bs[bb] + wv * 2048);    \
    gload16(ULR + (size_t)(n0 + srow + 16) * 1024 + k0_ + scol,                           \
            (char*)Bs[bb] + wv * 2048 + 1024);                                            \
  } while (0)
  f4v acc[4][4] = {};
  STGU(0, 0);
  STGU(1, 1);
  for (int kt = 0; kt < 32; ++kt) {
    const int cur = kt % 3;
    if (kt < 31) asm volatile("s_waitcnt vmcnt(4)" ::: "memory");
    else         asm volatile("s_waitcnt vmcnt(0)" ::: "memory");
    asm volatile("s_barrier" ::: "memory");
    if (kt + 2 < 32) STGU((kt + 2) % 3, kt + 2);
    s8v a[4], b[4];
#pragma unroll
    for (int m = 0; m < 4; ++m)
      a[m] = *(const s8v*)&As[cur][(wm * 64 + m * 16 + (lane & 15)) * 32 + (lane >> 4) * 8];
#pragma unroll
    for (int n = 0; n < 4; ++n)
      b[n] = *(const s8v*)&Bs[cur][(wn * 64 + n * 16 + (lane & 15)) * 32 + (lane >> 4) * 8];
#pragma unroll
    for (int m = 0; m < 4; ++m)
#pragma unroll
      for (int n = 0; n < 4; ++n) acc[m][n] = mfma16(a[m], b[n], acc[m][n]);
  }
#undef STGU
  const int gb = (n0 >> 1) + wn * 32;
#pragma unroll
  for (int m = 0; m < 4; ++m) {
    const int row = row0 + wm * 64 + m * 16 + (lane >> 4) * 4;
#pragma unroll
    for (int p = 0; p < 2; ++p) {
      const int gcol = gb + p * 16 + (lane & 15);
      const bool ok = gcol < NU;
      const float bl_ = ok ? lbias[gcol] : 0.f;
      const float br_ = ok ? rbias[gcol] : 0.f;
#pragma unroll
      for (int r = 0; r < 4; ++r) {
        float L = acc[m][2 * p][r] + bl_;
        float Rv = acc[m][2 * p + 1][r] + br_;
        float ge = 0.5f * Rv * (1.f + erff(Rv * 0.70710678118654752f));
        G[(size_t)(row + r) * NUP + gcol] = ok ? tobf(L * ge) : (unsigned short)0;
      }
    }
  }
}

// ---------------- down GEMM, 3-buffer pipelined: G @ down^T + bias -> output ----------------
__global__ __launch_bounds__(256) void down_gemm(
    const unsigned short* __restrict__ A, const unsigned short* __restrict__ Bt,
    const float* __restrict__ dbias, float* __restrict__ out) {
  __shared__ short As[3][4096];
  __shared__ short Bs[3][4096];
  const int tid = threadIdx.x, lane = tid & 63, wv = tid >> 6;
  const int wm = wv >> 1, wn = wv & 1;
  const int bid = blockIdx.x;
  const int swz = (bid & 7) * 64 + (bid >> 3);    // 512 = 8*64, bijective
  const int row0 = (swz >> 3) * 128, n0 = (swz & 7) * 128;
  const int srow = wv * 32 + (lane >> 2), scol = (lane & 3) * 8;
  const int NT = NUP / 32;  // 44
#define STGD(bb, kt_)                                                                     \
  do {                                                                                    \
    const int k0_ = (kt_) * 32;                                                           \
    gload16(A + (size_t)(row0 + srow) * NUP + k0_ + scol, (char*)As[bb] + wv * 2048);     \
    gload16(A + (size_t)(row0 + srow + 16) * NUP + k0_ + scol,                            \
            (char*)As[bb] + wv * 2048 + 1024);                                            \
    gload16(Bt + (size_t)(n0 + srow) * NUP + k0_ + scol, (char*)Bs[bb] + wv * 2048);      \
    gload16(Bt + (size_t)(n0 + srow + 16) * NUP + k0_ + scol,                             \
            (char*)Bs[bb] + wv * 2048 + 1024);                                            \
  } while (0)
  f4v acc[4][4] = {};
  STGD(0, 0);
  STGD(1, 1);
  for (int kt = 0; kt < NT; ++kt) {
    const int cur = kt % 3;
    if (kt < NT - 1) asm volatile("s_waitcnt vmcnt(4)" ::: "memory");
    else             asm volatile("s_waitcnt vmcnt(0)" ::: "memory");
    asm volatile("s_barrier" ::: "memory");
    if (kt + 2 < NT) STGD((kt + 2) % 3, kt + 2);
    s8v a[4], b[4];
#pragma unroll
    for (int m = 0; m < 4; ++m)
      a[m] = *(const s8v*)&As[cur][(wm * 64 + m * 16 + (lane & 15)) * 32 + (lane >> 4) * 8];
#pragma unroll
    for (int n = 0; n < 4; ++n)
      b[n] = *(const s8v*)&Bs[cur][(wn * 64 + n * 16 + (lane & 15)) * 32 + (lane >> 4) * 8];
#pragma unroll
    for (int m = 0; m < 4; ++m)
#pragma unroll
      for (int n = 0; n < 4; ++n) acc[m][n] = mfma16(a[m], b[n], acc[m][n]);
  }
#undef STGD
#pragma unroll
  for (int m = 0; m < 4; ++m) {
    const int row = row0 + wm * 64 + m * 16 + (lane >> 4) * 4;
#pragma unroll
    for (int n = 0; n < 4; ++n) {
      const int col = n0 + wn * 64 + n * 16 + (lane & 15);
      const float bias = dbias[col];
#pragma unroll
      for (int r = 0; r < 4; ++r)
        out[(size_t)(row + r) * ND + col] = acc[m][n][r] + bias;
    }
  }
}

extern "C" void kernel_launch(void* const* d_in, const int* in_sizes, int n_in,
                              void* d_out, int out_size, void* d_ws, size_t ws_size,
                              hipStream_t stream) {
  const float* x    = (const float*)d_in[0];
  const float* hp   = (const float*)d_in[1];
  const float* cp   = (const float*)d_in[2];
  const float* np_  = (const float*)d_in[3];
  const float* mp   = (const float*)d_in[4];
  const float* lg   = (const float*)d_in[5];
  const float* lb   = (const float*)d_in[6];
  const float* cw   = (const float*)d_in[7];
  const float* cb   = (const float*)d_in[8];
  const float* W    = (const float*)d_in[9];
  const float* bW   = (const float*)d_in[10];
  const float* R    = (const float*)d_in[11];
  const float* bR   = (const float*)d_in[12];
  const float* upl  = (const float*)d_in[13];
  const float* uplb = (const float*)d_in[14];
  const float* upr  = (const float*)d_in[15];
  const float* uprb = (const float*)d_in[16];
  const float* dwn  = (const float*)d_in[17];
  const float* dwnb = (const float*)d_in[18];
  float* out = (float*)d_out;
  char* ws = (char*)d_ws;
  unsigned short* Ag  = (unsigned short*)(ws + WS_AG);
  unsigned short* G   = (unsigned short*)(ws + WS_G);
  unsigned short* Hb  = (unsigned short*)(ws + WS_HBF);
  unsigned short* Wg  = (unsigned short*)(ws + WS_WG);
  unsigned short* ULR = (unsigned short*)(ws + WS_ULR);
  unsigned short* Dt  = (unsigned short*)(ws + WS_DWNT);

  prep_kernel<<<23040, 256, 0, stream>>>(W, R, upl, upr, dwn, Wg, ULR, Dt);
  norm_conv<<<NB, 256, 0, stream>>>(x, hp, lg, lb, cw, cb, Ag);
  gate_fused<<<dim3(64, 4, 8), 256, 0, stream>>>(Ag, Wg, bW, bR, cp, np_, mp, out, Hb);
  up_gemm<<<1408, 256, 0, stream>>>(Hb, ULR, uplb, uprb, G);
  down_gemm<<<512, 256, 0, stream>>>(G, Dt, dwnb, out);
}

// Round 13
// 249.240 us; speedup vs baseline: 1.1152x; 1.0625x over previous
//
#include <hip/hip_runtime.h>
#include <hip/hip_bf16.h>

typedef __attribute__((ext_vector_type(8))) short s8v;
typedef __attribute__((ext_vector_type(4))) float f4v;
typedef unsigned short us4 __attribute__((ext_vector_type(4)));

#define NB 8192
#define ND 1024
#define NH 8
#define NU 1365
#define NUP 1408
#define GK 384
#define GN 512
static const size_t BD = (size_t)NB * ND;

// workspace layout (bytes)
#define WS_AG   ((size_t)0)          // bf16 [8192][3072]  A-operand for gates
#define WS_G    ((size_t)50331648)   // bf16 [8192][1408]  gated-MLP intermediate
#define WS_HBF  ((size_t)73400320)   // bf16 [8192][1024]  h_t
#define WS_WG   ((size_t)90177536)   // bf16 [4096][384]   gate weights, gate-interleaved cols
#define WS_ULR  ((size_t)93323264)   // bf16 [2816][1024]  interleaved upL/upR^T (16-col groups)
#define WS_DWNT ((size_t)99090432)   // bf16 [1024][1408]  down^T padded

__device__ __forceinline__ void gload16(const void* g, void* l) {
  __builtin_amdgcn_global_load_lds((const __attribute__((address_space(1))) void*)g,
                                   (__attribute__((address_space(3))) void*)l, 16, 0, 0);
}
__device__ __forceinline__ unsigned short tobf(float f) {
  unsigned int u = __float_as_uint(f);
  unsigned int r = (u + 0x7FFFu + ((u >> 16) & 1u)) >> 16;
  return (unsigned short)r;
}
__device__ __forceinline__ float frcp(float x) { return __builtin_amdgcn_rcpf(x); }
__device__ __forceinline__ float fsigm(float x) { return frcp(1.f + __expf(-x)); }
__device__ __forceinline__ float ftanh(float x) {
  float e = __expf(2.f * x);
  return 1.f - 2.f * frcp(e + 1.f);
}
__device__ __forceinline__ f4v mfma16(s8v a, s8v b, f4v c) {
  return __builtin_amdgcn_mfma_f32_16x16x32_bf16(a, b, c, 0, 0, 0);
}

// ---------------- fused prep (weights) + norm_conv (LN+conv+SiLU) ----------------
// Blocks [0, 23040): weight pack/transpose/pad.  Blocks [23040, 31232): one row of
// LayerNorm + causal conv1d + SiLU each. Independent outputs; merged to overlap the
// many tiny prep blocks with norm's BW-bound blocks across CUs.
__global__ __launch_bounds__(256) void prep_norm(
    const float* __restrict__ W, const float* __restrict__ R,
    const float* __restrict__ upl, const float* __restrict__ upr,
    const float* __restrict__ dwn,
    const float* __restrict__ x, const float* __restrict__ hp,
    const float* __restrict__ lg, const float* __restrict__ lb,
    const float* __restrict__ cw, const float* __restrict__ cb,
    unsigned short* __restrict__ Wg, unsigned short* __restrict__ ULR,
    unsigned short* __restrict__ Dt, unsigned short* __restrict__ Ag) {
  if (blockIdx.x < 23040) {
    long long idx = (long long)blockIdx.x * 256 + threadIdx.x;
    const long long N1 = (long long)4096 * GK;
    const long long N3 = (long long)2 * NUP * ND;
    const long long N2 = (long long)NUP * ND;
    if (idx < N1) {
      int c = (int)(idx / GK), k = (int)(idx % GK);
      int j = c & 15, g = (c >> 4) & 3, cgrp = (c >> 6) & 7, h = c >> 9;
      int o = cgrp * 16 + j;
      float v = 0.f;
      if (k < 128) {
        if (g == 0 || g == 3) v = W[(((size_t)g * NH + h) * 128 + k) * 128 + o];
      } else if (k < 256) {
        if (g == 1 || g == 2) v = W[(((size_t)g * NH + h) * 128 + (k - 128)) * 128 + o];
      } else {
        v = R[(((size_t)g * NH + h) * 128 + (k - 256)) * 128 + o];
      }
      Wg[idx] = tobf(v);
      return;
    }
    idx -= N1;
    if (idx < N3) {
      int r = (int)(idx / ND), k = (int)(idx % ND);
      int o = (r >> 4) & 1;
      int gcol = (r >> 5) * 16 + (r & 15);
      float v = 0.f;
      if (gcol < NU) v = o ? upr[(size_t)k * NU + gcol] : upl[(size_t)k * NU + gcol];
      ULR[idx] = tobf(v);
      return;
    }
    idx -= N3;
    if (idx < N2) { int n = (int)(idx / NUP), k = (int)(idx % NUP);
      Dt[idx] = (k < NU) ? tobf(dwn[(size_t)k * ND + n]) : 0; }
    return;
  }
  // ---- norm_conv part ----
  const int b = blockIdx.x - 23040, tid = threadIdx.x;
  const int lane = tid & 63, wv = tid >> 6;
  __shared__ float xs[1024];
  __shared__ float red[8];
  const int d0 = tid * 4;
  float4 xv = *(const float4*)(x + (size_t)b * ND + d0);
  float s = xv.x + xv.y + xv.z + xv.w;
  float ss = xv.x * xv.x + xv.y * xv.y + xv.z * xv.z + xv.w * xv.w;
#pragma unroll
  for (int o = 32; o; o >>= 1) { s += __shfl_down(s, o); ss += __shfl_down(ss, o); }
  if (lane == 0) { red[wv] = s; red[4 + wv] = ss; }
  __syncthreads();
  float S = red[0] + red[1] + red[2] + red[3];
  float SS = red[4] + red[5] + red[6] + red[7];
  float mu = S * (1.f / ND);
  float var = SS * (1.f / ND) - mu * mu;
  float rstd = rsqrtf(var + 1e-5f);
  float xn[4];
#pragma unroll
  for (int t = 0; t < 4; ++t) {
    float xx = (&xv.x)[t];
    xn[t] = (xx - mu) * rstd * lg[d0 + t] + lb[d0 + t];
    xs[d0 + t] = xn[t];
  }
  __syncthreads();
  float w0 = cw[0], w1 = cw[1], w2 = cw[2], w3 = cw[3], cbv = cb[0];
  float cv[4];
#pragma unroll
  for (int t = 0; t < 4; ++t) {
    int d = d0 + t;
    float a = cbv + w3 * xs[d];
    if (d >= 1) a += w2 * xs[d - 1];
    if (d >= 2) a += w1 * xs[d - 2];
    if (d >= 3) a += w0 * xs[d - 3];
    cv[t] = a * fsigm(a);
  }
  float4 hv = *(const float4*)(hp + (size_t)b * ND + d0);
  const int h = d0 >> 7, j = d0 & 127;
  us4 px, pc, ph;
#pragma unroll
  for (int t = 0; t < 4; ++t) { px[t] = tobf((&xv.x)[t]); pc[t] = tobf(cv[t]); ph[t] = tobf((&hv.x)[t]); }
  size_t base = (size_t)b * 3072 + (size_t)h * 384 + j;
  *(us4*)(Ag + base) = px;
  *(us4*)(Ag + base + 128) = pc;
  *(us4*)(Ag + base + 256) = ph;
}

// ---------------- fused gate GEMM + sLSTM state update (R10-best structure) ----------------
// 1-phase LDS loop; gates on n-frag axis (in-register state math); c/n/m prefetch;
// fast transcendentals; zero-block elision; XCD-chunked 1D grid (p fastest -> the 4
// p-siblings sharing an Ag slice land on one XCD's L2).
__global__ __launch_bounds__(256) void gate_fused(
    const unsigned short* __restrict__ Ag, const unsigned short* __restrict__ Wg,
    const float* __restrict__ bW, const float* __restrict__ bR,
    const float* __restrict__ cp, const float* __restrict__ np_,
    const float* __restrict__ mp,
    float* __restrict__ dout, unsigned short* __restrict__ Hb) {
  __shared__ short As[128 * 32];   // 8KB
  __shared__ short Bs[128 * 32];   // 8KB
  const int tid = threadIdx.x, lane = tid & 63, wv = tid >> 6;
  const int wm = wv >> 1, wn = wv & 1;
  const int bid = blockIdx.x;
  const int swz = (bid & 7) * 256 + (bid >> 3);   // 2048 = 8*256, bijective XCD chunking
  const int p = swz & 3;                          // cgrp pair (fastest -> Ag-slice L2 reuse)
  const int h = (swz >> 2) & 7;
  const int row0 = (swz >> 5) * 128;
  const int srow = wv * 32 + (lane >> 2), scol = (lane & 3) * 8;
  const unsigned short* At = Ag + (size_t)h * 384;
  const unsigned short* Bt = Wg + ((size_t)h * 512 + (size_t)p * 128) * GK;
  const int cgrp = p * 2 + wn;
  const int gcol = h * 128 + cgrp * 16 + (lane & 15);
  float pc_[16], pn_[16], pm_[16];
#pragma unroll
  for (int m = 0; m < 4; ++m)
#pragma unroll
    for (int r = 0; r < 4; ++r) {
      const size_t idx = (size_t)(row0 + wm * 64 + m * 16 + (lane >> 4) * 4 + r) * ND + gcol;
      pc_[m * 4 + r] = cp[idx];
      pn_[m * 4 + r] = np_[idx];
      pm_[m * 4 + r] = mp[idx];
    }
  f4v acc[4][4] = {};
#pragma unroll
  for (int kt = 0; kt < 12; ++kt) {
    const int k0 = kt * 32;
    gload16(At + (size_t)(row0 + srow) * 3072 + k0 + scol, (char*)As + wv * 2048);
    gload16(At + (size_t)(row0 + srow + 16) * 3072 + k0 + scol, (char*)As + wv * 2048 + 1024);
    gload16(Bt + (size_t)srow * GK + k0 + scol, (char*)Bs + wv * 2048);
    gload16(Bt + (size_t)(srow + 16) * GK + k0 + scol, (char*)Bs + wv * 2048 + 1024);
    __syncthreads();
    s8v a[4];
#pragma unroll
    for (int m = 0; m < 4; ++m)
      a[m] = *(const s8v*)&As[(wm * 64 + m * 16 + (lane & 15)) * 32 + (lane >> 4) * 8];
#pragma unroll
    for (int g = 0; g < 4; ++g) {
      const bool active = (kt >= 8) || (kt < 4 ? (g == 0 || g == 3) : (g == 1 || g == 2));
      if (active) {
        s8v b = *(const s8v*)&Bs[(wn * 64 + g * 16 + (lane & 15)) * 32 + (lane >> 4) * 8];
#pragma unroll
        for (int m = 0; m < 4; ++m) acc[m][g] = mfma16(a[m], b, acc[m][g]);
      }
    }
    __syncthreads();
  }
  const float Bz = bW[gcol] + bR[gcol];
  const float Bi = bW[ND + gcol] + bR[ND + gcol];
  const float Bf = bW[2 * ND + gcol] + bR[2 * ND + gcol];
  const float Bo = bW[3 * ND + gcol] + bR[3 * ND + gcol];
#pragma unroll
  for (int m = 0; m < 4; ++m) {
    const int rbase = row0 + wm * 64 + m * 16 + (lane >> 4) * 4;
#pragma unroll
    for (int r = 0; r < 4; ++r) {
      const int e = m * 4 + r;
      const size_t idx = (size_t)(rbase + r) * ND + gcol;
      float zt = ftanh(acc[m][0][r] + Bz);
      float it = acc[m][1][r] + Bi;
      float ft = acc[m][2][r] + Bf;
      float ot = fsigm(acc[m][3][r] + Bo);
      float mv = pm_[e];
      float mt = fmaxf(ft + mv, it);
      float ii = __expf(it - mt);
      float ff = __expf(ft + mv - mt);
      float ct = ff * pc_[e] + ii * zt;
      float nt = ff * pn_[e] + ii;
      float ht = ot * ct * frcp(nt);
      dout[BD + idx] = ht;
      dout[2 * BD + idx] = ct;
      dout[3 * BD + idx] = nt;
      dout[4 * BD + idx] = mt;
      Hb[idx] = tobf(ht);
    }
  }
}

// ---------------- up GEMM with interleaved L/R B; fused glu epilogue -> bf16 G ----------------
// 1-phase m97 structure (measured best); 1D grid 1408, XCD-swizzled.
__global__ __launch_bounds__(256) void up_gemm(
    const unsigned short* __restrict__ A, const unsigned short* __restrict__ ULR,
    const float* __restrict__ lbias, const float* __restrict__ rbias,
    unsigned short* __restrict__ G) {
  __shared__ short As[4096];
  __shared__ short Bs[4096];
  const int tid = threadIdx.x, lane = tid & 63, wv = tid >> 6;
  const int wm = wv >> 1, wn = wv & 1;
  const int bid = blockIdx.x;
  const int swz = (bid & 7) * 176 + (bid >> 3);   // 1408 = 8*176, bijective
  const int row0 = (swz / 22) * 128, n0 = (swz % 22) * 128;
  const int srow = wv * 32 + (lane >> 2), scol = (lane & 3) * 8;
  f4v acc[4][4] = {};
  for (int kt = 0; kt < 32; ++kt) {
    const int k0 = kt * 32;
    gload16(A + (size_t)(row0 + srow) * 1024 + k0 + scol, (char*)As + wv * 2048);
    gload16(A + (size_t)(row0 + srow + 16) * 1024 + k0 + scol, (char*)As + wv * 2048 + 1024);
    gload16(ULR + (size_t)(n0 + srow) * 1024 + k0 + scol, (char*)Bs + wv * 2048);
    gload16(ULR + (size_t)(n0 + srow + 16) * 1024 + k0 + scol, (char*)Bs + wv * 2048 + 1024);
    __syncthreads();
    s8v a[4], b[4];
#pragma unroll
    for (int m = 0; m < 4; ++m) a[m] = *(const s8v*)&As[(wm * 64 + m * 16 + (lane & 15)) * 32 + (lane >> 4) * 8];
#pragma unroll
    for (int n = 0; n < 4; ++n) b[n] = *(const s8v*)&Bs[(wn * 64 + n * 16 + (lane & 15)) * 32 + (lane >> 4) * 8];
#pragma unroll
    for (int m = 0; m < 4; ++m)
#pragma unroll
      for (int n = 0; n < 4; ++n) acc[m][n] = mfma16(a[m], b[n], acc[m][n]);
    __syncthreads();
  }
  const int gb = (n0 >> 1) + wn * 32;
#pragma unroll
  for (int m = 0; m < 4; ++m) {
    const int row = row0 + wm * 64 + m * 16 + (lane >> 4) * 4;
#pragma unroll
    for (int p = 0; p < 2; ++p) {
      const int gcol = gb + p * 16 + (lane & 15);
      const bool ok = gcol < NU;
      const float bl_ = ok ? lbias[gcol] : 0.f;
      const float br_ = ok ? rbias[gcol] : 0.f;
#pragma unroll
      for (int r = 0; r < 4; ++r) {
        float L = acc[m][2 * p][r] + bl_;
        float Rv = acc[m][2 * p + 1][r] + br_;
        float ge = 0.5f * Rv * (1.f + erff(Rv * 0.70710678118654752f));
        G[(size_t)(row + r) * NUP + gcol] = ok ? tobf(L * ge) : (unsigned short)0;
      }
    }
  }
}

// ---------------- down GEMM: G @ down^T + bias -> output (1-phase) ----------------
__global__ __launch_bounds__(256) void down_gemm(
    const unsigned short* __restrict__ A, const unsigned short* __restrict__ Bt,
    const float* __restrict__ dbias, float* __restrict__ out) {
  __shared__ short As[4096];
  __shared__ short Bs[4096];
  const int tid = threadIdx.x, lane = tid & 63, wv = tid >> 6;
  const int wm = wv >> 1, wn = wv & 1;
  const int bid = blockIdx.x;
  const int swz = (bid & 7) * 64 + (bid >> 3);    // 512 = 8*64, bijective
  const int row0 = (swz >> 3) * 128, n0 = (swz & 7) * 128;
  const int srow = wv * 32 + (lane >> 2), scol = (lane & 3) * 8;
  f4v acc[4][4] = {};
  for (int kt = 0; kt < NUP / 32; ++kt) {
    const int k0 = kt * 32;
    gload16(A + (size_t)(row0 + srow) * NUP + k0 + scol, (char*)As + wv * 2048);
    gload16(A + (size_t)(row0 + srow + 16) * NUP + k0 + scol, (char*)As + wv * 2048 + 1024);
    gload16(Bt + (size_t)(n0 + srow) * NUP + k0 + scol, (char*)Bs + wv * 2048);
    gload16(Bt + (size_t)(n0 + srow + 16) * NUP + k0 + scol, (char*)Bs + wv * 2048 + 1024);
    __syncthreads();
    s8v a[4], b[4];
#pragma unroll
    for (int m = 0; m < 4; ++m) a[m] = *(const s8v*)&As[(wm * 64 + m * 16 + (lane & 15)) * 32 + (lane >> 4) * 8];
#pragma unroll
    for (int n = 0; n < 4; ++n) b[n] = *(const s8v*)&Bs[(wn * 64 + n * 16 + (lane & 15)) * 32 + (lane >> 4) * 8];
#pragma unroll
    for (int m = 0; m < 4; ++m)
#pragma unroll
      for (int n = 0; n < 4; ++n) acc[m][n] = mfma16(a[m], b[n], acc[m][n]);
    __syncthreads();
  }
#pragma unroll
  for (int m = 0; m < 4; ++m) {
    const int row = row0 + wm * 64 + m * 16 + (lane >> 4) * 4;
#pragma unroll
    for (int n = 0; n < 4; ++n) {
      const int col = n0 + wn * 64 + n * 16 + (lane & 15);
      const float bias = dbias[col];
#pragma unroll
      for (int r = 0; r < 4; ++r)
        out[(size_t)(row + r) * ND + col] = acc[m][n][r] + bias;
    }
  }
}

extern "C" void kernel_launch(void* const* d_in, const int* in_sizes, int n_in,
                              void* d_out, int out_size, void* d_ws, size_t ws_size,
                              hipStream_t stream) {
  const float* x    = (const float*)d_in[0];
  const float* hp   = (const float*)d_in[1];
  const float* cp   = (const float*)d_in[2];
  const float* np_  = (const float*)d_in[3];
  const float* mp   = (const float*)d_in[4];
  const float* lg   = (const float*)d_in[5];
  const float* lb   = (const float*)d_in[6];
  const float* cw   = (const float*)d_in[7];
  const float* cb   = (const float*)d_in[8];
  const float* W    = (const float*)d_in[9];
  const float* bW   = (const float*)d_in[10];
  const float* R    = (const float*)d_in[11];
  const float* bR   = (const float*)d_in[12];
  const float* upl  = (const float*)d_in[13];
  const float* uplb = (const float*)d_in[14];
  const float* upr  = (const float*)d_in[15];
  const float* uprb = (const float*)d_in[16];
  const float* dwn  = (const float*)d_in[17];
  const float* dwnb = (const float*)d_in[18];
  float* out = (float*)d_out;
  char* ws = (char*)d_ws;
  unsigned short* Ag  = (unsigned short*)(ws + WS_AG);
  unsigned short* G   = (unsigned short*)(ws + WS_G);
  unsigned short* Hb  = (unsigned short*)(ws + WS_HBF);
  unsigned short* Wg  = (unsigned short*)(ws + WS_WG);
  unsigned short* ULR = (unsigned short*)(ws + WS_ULR);
  unsigned short* Dt  = (unsigned short*)(ws + WS_DWNT);

  prep_norm<<<23040 + NB, 256, 0, stream>>>(W, R, upl, upr, dwn, x, hp, lg, lb, cw, cb,
                                            Wg, ULR, Dt, Ag);
  gate_fused<<<2048, 256, 0, stream>>>(Ag, Wg, bW, bR, cp, np_, mp, out, Hb);
  up_gemm<<<1408, 256, 0, stream>>>(Hb, ULR, uplb, uprb, G);
  down_gemm<<<512, 256, 0, stream>>>(G, Dt, dwnb, out);
}